// Round 12
// baseline (1788.330 us; speedup 1.0000x reference)
//
#include <hip/hip_runtime.h>
#include <cstdint>
#include <cstddef>

#define NTOK 4096
#define DMODEL 2048
#define HIDDEN 8192
#define TOPK_K 1024
#define NCAND 160
#define BLAS_KC 320   // OpenBLAS SGEMM_DEFAULT_Q (SKX route) -- verified round 7
#define NSEG 7        // ceil(2048/320): segments of the BLAS accumulation chain

typedef __fp16 f16;
typedef __fp16 half8v __attribute__((ext_vector_type(8)));
typedef float f32x4 __attribute__((ext_vector_type(4)));

__device__ __forceinline__ void gload_lds16(const void* gptr, void* lptr) {
  __builtin_amdgcn_global_load_lds(
      (const __attribute__((address_space(1))) void*)gptr,
      (__attribute__((address_space(3))) void*)lptr, 16, 0, 0);
}

__device__ __forceinline__ unsigned sortable_key(float f) {
  unsigned u = __float_as_uint(f);
  return (u >> 31) ? ~u : (u | 0x80000000u);
}
__device__ __forceinline__ float unkey(unsigned k) {
  unsigned u = (k & 0x80000000u) ? (k ^ 0x80000000u) : ~k;
  return __uint_as_float(u);
}

// ---- Global+LDS swizzle convention (T2): within each (row, 64-col block),
// logical 16B slot q lives at physical slot q ^ (row & 7).
__device__ __forceinline__ half8v frag_read(const f16* __restrict__ lds, int R,
                                            int ks, int l) {
  return *reinterpret_cast<const half8v*>(
      &lds[R * 64 + ((((ks * 4) + (l >> 4)) ^ (l & 7)) * 8)]);
}

// ---------------- cast fp32 -> f16 with swizzled layout ---------------------
__global__ __launch_bounds__(256)
void cast_swz(const float* __restrict__ in, f16* __restrict__ out, int K, int n8) {
  const int stride = gridDim.x * blockDim.x;
  const int gpr = K >> 3;
  for (int i = blockIdx.x * blockDim.x + threadIdx.x; i < n8; i += stride) {
    const int row = i / gpr;
    const int gi = i - row * gpr;
    const int cb = (gi >> 3) << 6;
    const int ps = (gi & 7) ^ (row & 7);
    const float* s = in + (size_t)row * K + cb + ((gi & 7) << 3);
    float4 v0 = *reinterpret_cast<const float4*>(s);
    float4 v1 = *reinterpret_cast<const float4*>(s + 4);
    half8v h = {(f16)v0.x, (f16)v0.y, (f16)v0.z, (f16)v0.w,
                (f16)v1.x, (f16)v1.y, (f16)v1.z, (f16)v1.w};
    *reinterpret_cast<half8v*>(out + (size_t)row * K + cb + (ps << 3)) = h;
  }
}

// ---------------- fused up+gate GEMM (f16 operands, gload_lds staging) ------
__global__ __launch_bounds__(256, 2)
void gemm_upgate(const f16* __restrict__ X16, const f16* __restrict__ Wg16,
                 const f16* __restrict__ Wu16, f16* __restrict__ G16,
                 f16* __restrict__ Hid) {
  __shared__ f16 As[128 * 64];
  __shared__ f16 Bgs[128 * 64];
  __shared__ f16 Bus[128 * 64];
  const int nwg = gridDim.x;
  const int bid = blockIdx.x;
  const int wg = (bid & 7) * (nwg >> 3) + (bid >> 3);
  const int NT = HIDDEN >> 7;
  const int bm = wg / NT, bn = wg % NT;
  const int tid = threadIdx.x;
  const int w = tid >> 6, l = tid & 63;
  const int wr = w >> 1, wc = w & 1;
  const int lr = l >> 3, lc8 = (l & 7) << 3;

  f32x4 accg[4][4] = {};
  f32x4 accu[4][4] = {};

  for (int kt = 0; kt < DMODEL; kt += 64) {
    __syncthreads();
#pragma unroll
    for (int i = 0; i < 4; ++i) {
      const int row = i * 32 + w * 8;
      gload_lds16(X16 + (size_t)(bm * 128 + row + lr) * DMODEL + kt + lc8, &As[row * 64]);
      gload_lds16(Wg16 + (size_t)(bn * 128 + row + lr) * DMODEL + kt + lc8, &Bgs[row * 64]);
      gload_lds16(Wu16 + (size_t)(bn * 128 + row + lr) * DMODEL + kt + lc8, &Bus[row * 64]);
    }
    __syncthreads();
#pragma unroll
    for (int ks = 0; ks < 2; ++ks) {
      half8v af[4], bg[4], bu[4];
#pragma unroll
      for (int mf = 0; mf < 4; ++mf)
        af[mf] = frag_read(As, wr * 64 + mf * 16 + (l & 15), ks, l);
#pragma unroll
      for (int nf = 0; nf < 4; ++nf) {
        bg[nf] = frag_read(Bgs, wc * 64 + nf * 16 + (l & 15), ks, l);
        bu[nf] = frag_read(Bus, wc * 64 + nf * 16 + (l & 15), ks, l);
      }
#pragma unroll
      for (int mf = 0; mf < 4; ++mf)
#pragma unroll
        for (int nf = 0; nf < 4; ++nf) {
          accg[mf][nf] = __builtin_amdgcn_mfma_f32_16x16x32_f16(af[mf], bg[nf], accg[mf][nf], 0, 0, 0);
          accu[mf][nf] = __builtin_amdgcn_mfma_f32_16x16x32_f16(af[mf], bu[nf], accu[mf][nf], 0, 0, 0);
        }
    }
  }

  const int row0 = bm * 128 + wr * 64 + (l >> 4) * 4;
  const int col0 = bn * 128 + wc * 64 + (l & 15);
#pragma unroll
  for (int mf = 0; mf < 4; ++mf)
#pragma unroll
    for (int nf = 0; nf < 4; ++nf)
#pragma unroll
      for (int j = 0; j < 4; ++j) {
        const int rr = row0 + mf * 16 + j;
        const int cc = col0 + nf * 16;
        const int pcc = (cc & ~63) | (cc & 7) | (((((cc >> 3) & 7) ^ (rr & 7))) << 3);
        const size_t idx = (size_t)rr * HIDDEN + pcc;
        G16[idx] = (f16)accg[mf][nf][j];
        Hid[idx] = (f16)accu[mf][nf][j];
      }
}

// ---------------- top-k -> bitmap -------------------------------------------
// Round-9-proven structure: float gv staging + 4-pass 32-bit-key radix with
// serial tid0 bucket selection. Diffs vs round 9 (both equivalence-preserving):
//   (1) per-wave histograms hist4[4][256], summed at selection;
//   (2) segment-parallel BLAS-emulated candidate dots (bit-identical chains).
__global__ __launch_bounds__(256)
void topk_mask(const f16* __restrict__ G16, const float* __restrict__ X,
               const float* __restrict__ Wg, unsigned* __restrict__ Mask,
               int H, int K) {
  __shared__ float gv[HIDDEN];           // 32 KB, logical order
  __shared__ int hist4[4][256];          // per-wave histograms
  __shared__ int bsel[2];
  __shared__ unsigned bmap[HIDDEN / 32];
  __shared__ int cnt[2];
  __shared__ int cidx[NCAND];
  __shared__ float cpart[NCAND][NSEG];
  __shared__ float cval[NCAND];
  const int r = blockIdx.x;
  const int tid = threadIdx.x;
  const int w = tid >> 6;
  const f16* grow = G16 + (size_t)r * H;

  // stage float values (unswizzle the G16 layout) -- identical to round 9
  for (int i = tid; i < H / 8; i += 256) {
    half8v v = reinterpret_cast<const half8v*>(grow)[i];
    const int ls = (i & 7) ^ (r & 7);
    const int c8l = ((i >> 3) << 6) | (ls << 3);
#pragma unroll
    for (int j = 0; j < 8; ++j) gv[c8l + j] = (float)v[j];
  }
  if (tid < 2) cnt[tid] = 0;
  __syncthreads();

  // 4-pass radix select of k-th largest (32-bit sortable keys, round-9-proven)
  unsigned pval = 0;
  int remaining = K;
  for (int pass = 0; pass < 4; ++pass) {
    const int shift = 24 - pass * 8;
    const unsigned pmask = (pass == 0) ? 0u : (0xFFFFFFFFu << (32 - 8 * pass));
    for (int b = tid; b < 1024; b += 256) ((int*)hist4)[b] = 0;
    __syncthreads();
    for (int i = tid; i < H; i += 256) {
      unsigned kk = sortable_key(gv[i]);
      if ((kk & pmask) == pval) atomicAdd(&hist4[w][(kk >> shift) & 255], 1);
    }
    __syncthreads();
    if (tid == 0) {
      int cum = 0, b = 255;
      for (; b > 0; --b) {
        int c = hist4[0][b] + hist4[1][b] + hist4[2][b] + hist4[3][b];
        if (cum + c >= remaining) break;
        cum += c;
      }
      bsel[0] = b;
      bsel[1] = cum;
    }
    __syncthreads();
    pval |= ((unsigned)bsel[0]) << shift;
    remaining -= bsel[1];
    __syncthreads();
  }
  const float Tval = unkey(pval);
  // |float(g16) - g_blas| <= e ~ 2.5e-3; DELTA >= 2e required, 6e-3 margin.
  const float DELTA = 6e-3f;

  // classification: thread t owns elements [t*32, t*32+32) -> one bitmap word
  unsigned word = 0;
  for (int j = 0; j < 32; ++j) {
    const int h = tid * 32 + j;
    const float v = gv[h];
    if (v > Tval + DELTA) {
      word |= 1u << j;
    } else if (v >= Tval - DELTA) {
      int c = atomicAdd(&cnt[0], 1);
      if (c < NCAND) cidx[c] = h;
    }
  }
  bmap[tid] = word;
  atomicAdd(&cnt[1], __popc(word));
  __syncthreads();

  const int m = min(cnt[0], NCAND);
  const int need = max(K - cnt[1], 0);
  const float* xrow = X + (size_t)r * DMODEL;

  // segment-parallel BLAS-emulated dots: 7 threads per candidate, each runs
  // one kc=320 sequential-FMA chain; partials combined ascending with
  // __fadd_rn -- bit-identical to the round-7-verified blas_emu_dot.
  for (int t = tid; t < m * NSEG; t += 256) {
    const int c = t / NSEG, s = t - (t / NSEG) * NSEG;
    const int kb = s * BLAS_KC;
    const int ke = (kb + BLAS_KC < DMODEL) ? kb + BLAS_KC : DMODEL;
    const float* wrow = Wg + (size_t)cidx[c] * DMODEL;
    float acc = 0.0f;
    for (int k = kb; k < ke; ++k)
      acc = __builtin_fmaf(xrow[k], wrow[k], acc);
    cpart[c][s] = acc;
  }
  __syncthreads();
  for (int c = tid; c < m; c += 256) {
    float ctot = cpart[c][0];
#pragma unroll
    for (int s = 1; s < NSEG; ++s) ctot = __fadd_rn(ctot, cpart[c][s]);
    cval[c] = ctot;
  }
  __syncthreads();

  // pick top `need` among candidates by (emulated value desc, index asc)
  if (tid == 0) {
    for (int s = 0; s < need; ++s) {
      int best = -1;
      float bv = 0.0f;
      int bix = 0x7fffffff;
      for (int c = 0; c < m; ++c) {
        float v = cval[c];
        if (v <= -1.0e29f) continue;
        if (best < 0 || v > bv || (v == bv && cidx[c] < bix)) {
          bv = v; bix = cidx[c]; best = c;
        }
      }
      if (best < 0) break;
      atomicOr(&bmap[cidx[best] >> 5], 1u << (cidx[best] & 31));
      cval[best] = -1.0e30f;
    }
  }
  __syncthreads();
  Mask[(size_t)r * (H / 32) + tid] = bmap[tid];
}

// ---------------- mask + silu in-place on Hid (swizzled layout) -------------
__global__ __launch_bounds__(256)
void mask_silu(f16* __restrict__ P, const f16* __restrict__ G16,
               const unsigned* __restrict__ Msk, int n8) {
  const int stride = gridDim.x * blockDim.x;
  for (int i = blockIdx.x * blockDim.x + threadIdx.x; i < n8; i += stride) {
    const int row = i >> 10;
    const int gi = i & 1023;
    const int ls = (gi & 7) ^ (row & 7);
    const int c8l = ((gi >> 3) << 6) | (ls << 3);
    const unsigned mw = Msk[((size_t)row << 8) + (c8l >> 5)];
    const unsigned bits = (mw >> (c8l & 31)) & 0xFFu;
    half8v h = reinterpret_cast<half8v*>(P)[i];
    half8v g = reinterpret_cast<const half8v*>(G16)[i];
    half8v o;
#pragma unroll
    for (int j = 0; j < 8; ++j) {
      float gg = (float)g[j];
      float act = gg / (1.0f + __expf(-gg));
      o[j] = ((bits >> j) & 1u) ? (f16)((float)h[j] * act) : (f16)0.0f;
    }
    reinterpret_cast<half8v*>(P)[i] = o;
  }
}

// ---------------- down GEMM: out = p @ w_down^T (both f16, swizzled) --------
__global__ __launch_bounds__(256, 2)
void gemm_down(const f16* __restrict__ A, const f16* __restrict__ B16,
               float* __restrict__ C) {
  __shared__ f16 As[128 * 64];
  __shared__ f16 Bs[128 * 64];
  const int nwg = gridDim.x;
  const int bid = blockIdx.x;
  const int wg = (bid & 7) * (nwg >> 3) + (bid >> 3);
  const int NT = DMODEL >> 7;
  const int bm = wg / NT, bn = wg % NT;
  const int tid = threadIdx.x;
  const int w = tid >> 6, l = tid & 63;
  const int wr = w >> 1, wc = w & 1;
  const int lr = l >> 3, lc8 = (l & 7) << 3;

  f32x4 acc[4][4] = {};

  for (int kt = 0; kt < HIDDEN; kt += 64) {
    __syncthreads();
#pragma unroll
    for (int i = 0; i < 4; ++i) {
      const int row = i * 32 + w * 8;
      gload_lds16(A + (size_t)(bm * 128 + row + lr) * HIDDEN + kt + lc8, &As[row * 64]);
      gload_lds16(B16 + (size_t)(bn * 128 + row + lr) * HIDDEN + kt + lc8, &Bs[row * 64]);
    }
    __syncthreads();
#pragma unroll
    for (int ks = 0; ks < 2; ++ks) {
      half8v af[4], bf[4];
#pragma unroll
      for (int mf = 0; mf < 4; ++mf)
        af[mf] = frag_read(As, wr * 64 + mf * 16 + (l & 15), ks, l);
#pragma unroll
      for (int nf = 0; nf < 4; ++nf)
        bf[nf] = frag_read(Bs, wc * 64 + nf * 16 + (l & 15), ks, l);
#pragma unroll
      for (int mf = 0; mf < 4; ++mf)
#pragma unroll
        for (int nf = 0; nf < 4; ++nf)
          acc[mf][nf] = __builtin_amdgcn_mfma_f32_16x16x32_f16(af[mf], bf[nf], acc[mf][nf], 0, 0, 0);
    }
  }

  const int row0 = bm * 128 + wr * 64 + (l >> 4) * 4;
  const int col0 = bn * 128 + wc * 64 + (l & 15);
#pragma unroll
  for (int mf = 0; mf < 4; ++mf)
#pragma unroll
    for (int nf = 0; nf < 4; ++nf)
#pragma unroll
      for (int j = 0; j < 4; ++j)
        C[(size_t)(row0 + mf * 16 + j) * DMODEL + (col0 + nf * 16)] = acc[mf][nf][j];
}

// ---------------- launch ----------------
extern "C" void kernel_launch(void* const* d_in, const int* in_sizes, int n_in,
                              void* d_out, int out_size, void* d_ws, size_t ws_size,
                              hipStream_t stream) {
  const float* x = (const float*)d_in[0];
  const float* w_up = (const float*)d_in[1];
  const float* w_gate = (const float*)d_in[2];
  const float* w_down = (const float*)d_in[3];
  float* out = (float*)d_out;

  const size_t g_bytes = (size_t)NTOK * HIDDEN * 2;
  const size_t p_bytes = (size_t)NTOK * HIDDEN * 2;
  const size_t m_bytes = (size_t)NTOK * (HIDDEN / 32) * 4;
  const size_t x16_b = (size_t)NTOK * DMODEL * 2;
  const size_t wg16_b = (size_t)HIDDEN * DMODEL * 2;
  const size_t wu16_b = (size_t)HIDDEN * DMODEL * 2;
  const size_t wd16_b = (size_t)DMODEL * HIDDEN * 2;
  if (ws_size < g_bytes + p_bytes + m_bytes + x16_b + wg16_b + wu16_b + wd16_b) {
    hipMemsetAsync(d_out, 0, (size_t)out_size * 4, stream);
    return;
  }

  char* p = (char*)d_ws;
  f16* g16 = (f16*)p;       p += g_bytes;
  f16* pbuf = (f16*)p;      p += p_bytes;
  unsigned* msk = (unsigned*)p; p += m_bytes;
  f16* x16 = (f16*)p;       p += x16_b;
  f16* wg16 = (f16*)p;      p += wg16_b;
  f16* wu16 = (f16*)p;      p += wu16_b;
  f16* wd16 = (f16*)p;

  dim3 blk(256);

  cast_swz<<<2048, blk, 0, stream>>>(x, x16, DMODEL, NTOK * DMODEL / 8);
  cast_swz<<<2048, blk, 0, stream>>>(w_gate, wg16, DMODEL, HIDDEN * DMODEL / 8);
  cast_swz<<<2048, blk, 0, stream>>>(w_up, wu16, DMODEL, HIDDEN * DMODEL / 8);
  cast_swz<<<2048, blk, 0, stream>>>(w_down, wd16, HIDDEN, DMODEL * HIDDEN / 8);

  gemm_upgate<<<(NTOK / 128) * (HIDDEN / 128), blk, 0, stream>>>(
      x16, wg16, wu16, g16, pbuf);

  topk_mask<<<NTOK, blk, 0, stream>>>(g16, x, w_gate, msk, HIDDEN, TOPK_K);

  mask_silu<<<2048, blk, 0, stream>>>(pbuf, g16, msk, NTOK * HIDDEN / 8);

  gemm_down<<<(NTOK / 128) * (DMODEL / 128), blk, 0, stream>>>(pbuf, wd16, out);
}

// Round 13
// 1773.419 us; speedup vs baseline: 1.0084x; 1.0084x over previous
//
#include <hip/hip_runtime.h>
#include <cstdint>
#include <cstddef>

#define NTOK 4096
#define DMODEL 2048
#define HIDDEN 8192
#define TOPK_K 1024
#define NCAND 128
#define BLAS_KC 320   // OpenBLAS SGEMM_DEFAULT_Q (SKX route) -- verified round 7
#define NSEG 7        // ceil(2048/320): segments of the BLAS accumulation chain

typedef __fp16 f16;
typedef __fp16 half8v __attribute__((ext_vector_type(8)));
typedef float f32x4 __attribute__((ext_vector_type(4)));

__device__ __forceinline__ void gload_lds16(const void* gptr, void* lptr) {
  __builtin_amdgcn_global_load_lds(
      (const __attribute__((address_space(1))) void*)gptr,
      (__attribute__((address_space(3))) void*)lptr, 16, 0, 0);
}

__device__ __forceinline__ unsigned sortable_key(float f) {
  unsigned u = __float_as_uint(f);
  return (u >> 31) ? ~u : (u | 0x80000000u);
}
__device__ __forceinline__ float unkey(unsigned k) {
  unsigned u = (k & 0x80000000u) ? (k ^ 0x80000000u) : ~k;
  return __uint_as_float(u);
}

// ---- Global+LDS swizzle convention (T2): within each (row, 64-col block),
// logical 16B slot q lives at physical slot q ^ (row & 7).
__device__ __forceinline__ half8v frag_read(const f16* __restrict__ lds, int R,
                                            int ks, int l) {
  return *reinterpret_cast<const half8v*>(
      &lds[R * 64 + ((((ks * 4) + (l >> 4)) ^ (l & 7)) * 8)]);
}

// ---------------- cast fp32 -> f16 with swizzled layout ---------------------
__global__ __launch_bounds__(256)
void cast_swz(const float* __restrict__ in, f16* __restrict__ out, int K, int n8) {
  const int stride = gridDim.x * blockDim.x;
  const int gpr = K >> 3;
  for (int i = blockIdx.x * blockDim.x + threadIdx.x; i < n8; i += stride) {
    const int row = i / gpr;
    const int gi = i - row * gpr;
    const int cb = (gi >> 3) << 6;
    const int ps = (gi & 7) ^ (row & 7);
    const float* s = in + (size_t)row * K + cb + ((gi & 7) << 3);
    float4 v0 = *reinterpret_cast<const float4*>(s);
    float4 v1 = *reinterpret_cast<const float4*>(s + 4);
    half8v h = {(f16)v0.x, (f16)v0.y, (f16)v0.z, (f16)v0.w,
                (f16)v1.x, (f16)v1.y, (f16)v1.z, (f16)v1.w};
    *reinterpret_cast<half8v*>(out + (size_t)row * K + cb + (ps << 3)) = h;
  }
}

// ---------------- fused up+gate GEMM (f16 operands, gload_lds staging) ------
__global__ __launch_bounds__(256, 2)
void gemm_upgate(const f16* __restrict__ X16, const f16* __restrict__ Wg16,
                 const f16* __restrict__ Wu16, f16* __restrict__ G16,
                 f16* __restrict__ Hid) {
  __shared__ f16 As[128 * 64];
  __shared__ f16 Bgs[128 * 64];
  __shared__ f16 Bus[128 * 64];
  const int nwg = gridDim.x;
  const int bid = blockIdx.x;
  const int wg = (bid & 7) * (nwg >> 3) + (bid >> 3);
  const int NT = HIDDEN >> 7;
  const int bm = wg / NT, bn = wg % NT;
  const int tid = threadIdx.x;
  const int w = tid >> 6, l = tid & 63;
  const int wr = w >> 1, wc = w & 1;
  const int lr = l >> 3, lc8 = (l & 7) << 3;

  f32x4 accg[4][4] = {};
  f32x4 accu[4][4] = {};

  for (int kt = 0; kt < DMODEL; kt += 64) {
    __syncthreads();
#pragma unroll
    for (int i = 0; i < 4; ++i) {
      const int row = i * 32 + w * 8;
      gload_lds16(X16 + (size_t)(bm * 128 + row + lr) * DMODEL + kt + lc8, &As[row * 64]);
      gload_lds16(Wg16 + (size_t)(bn * 128 + row + lr) * DMODEL + kt + lc8, &Bgs[row * 64]);
      gload_lds16(Wu16 + (size_t)(bn * 128 + row + lr) * DMODEL + kt + lc8, &Bus[row * 64]);
    }
    __syncthreads();
#pragma unroll
    for (int ks = 0; ks < 2; ++ks) {
      half8v af[4], bg[4], bu[4];
#pragma unroll
      for (int mf = 0; mf < 4; ++mf)
        af[mf] = frag_read(As, wr * 64 + mf * 16 + (l & 15), ks, l);
#pragma unroll
      for (int nf = 0; nf < 4; ++nf) {
        bg[nf] = frag_read(Bgs, wc * 64 + nf * 16 + (l & 15), ks, l);
        bu[nf] = frag_read(Bus, wc * 64 + nf * 16 + (l & 15), ks, l);
      }
#pragma unroll
      for (int mf = 0; mf < 4; ++mf)
#pragma unroll
        for (int nf = 0; nf < 4; ++nf) {
          accg[mf][nf] = __builtin_amdgcn_mfma_f32_16x16x32_f16(af[mf], bg[nf], accg[mf][nf], 0, 0, 0);
          accu[mf][nf] = __builtin_amdgcn_mfma_f32_16x16x32_f16(af[mf], bu[nf], accu[mf][nf], 0, 0, 0);
        }
    }
  }

  const int row0 = bm * 128 + wr * 64 + (l >> 4) * 4;
  const int col0 = bn * 128 + wc * 64 + (l & 15);
#pragma unroll
  for (int mf = 0; mf < 4; ++mf)
#pragma unroll
    for (int nf = 0; nf < 4; ++nf)
#pragma unroll
      for (int j = 0; j < 4; ++j) {
        const int rr = row0 + mf * 16 + j;
        const int cc = col0 + nf * 16;
        const int pcc = (cc & ~63) | (cc & 7) | (((((cc >> 3) & 7) ^ (rr & 7))) << 3);
        const size_t idx = (size_t)rr * HIDDEN + pcc;
        G16[idx] = (f16)accg[mf][nf][j];
        Hid[idx] = (f16)accu[mf][nf][j];
      }
}

// ---------------- top-k -> bitmap -------------------------------------------
// Round-9-proven radix core (float gv staging, single hist, serial tid0
// selection). Diffs vs round 9, each independently verified:
//   (1) segment-parallel BLAS-emulated candidate dots (ran correct in r12);
//   (2) XOR-permuted classification read order (same (elem,bit) pairs,
//       removes the 64-way gv bank conflict);
//   (3) NCAND 128 -> LDS 39.4 KB -> 4 blocks/CU.
__global__ __launch_bounds__(256)
void topk_mask(const f16* __restrict__ G16, const float* __restrict__ X,
               const float* __restrict__ Wg, unsigned* __restrict__ Mask,
               int H, int K) {
  __shared__ float gv[HIDDEN];           // 32 KB, logical order
  __shared__ int hist[256];
  __shared__ int bsel[2];
  __shared__ unsigned bmap[HIDDEN / 32];
  __shared__ int cnt[2];
  __shared__ int cidx[NCAND];
  __shared__ float cpart[NCAND][NSEG];
  __shared__ float cval[NCAND];
  const int r = blockIdx.x;
  const int tid = threadIdx.x;
  const f16* grow = G16 + (size_t)r * H;

  // stage float values (unswizzle the G16 layout) -- identical to round 9
  for (int i = tid; i < H / 8; i += 256) {
    half8v v = reinterpret_cast<const half8v*>(grow)[i];
    const int ls = (i & 7) ^ (r & 7);
    const int c8l = ((i >> 3) << 6) | (ls << 3);
#pragma unroll
    for (int j = 0; j < 8; ++j) gv[c8l + j] = (float)v[j];
  }
  if (tid < 2) cnt[tid] = 0;
  __syncthreads();

  // 4-pass radix select of k-th largest (round-9-proven, verbatim)
  unsigned pval = 0;
  int remaining = K;
  for (int pass = 0; pass < 4; ++pass) {
    const int shift = 24 - pass * 8;
    const unsigned pmask = (pass == 0) ? 0u : (0xFFFFFFFFu << (32 - 8 * pass));
    hist[tid] = 0;
    __syncthreads();
    for (int i = tid; i < H; i += 256) {
      unsigned kk = sortable_key(gv[i]);
      if ((kk & pmask) == pval) atomicAdd(&hist[(kk >> shift) & 255], 1);
    }
    __syncthreads();
    if (tid == 0) {
      int cum = 0, b = 255;
      for (; b > 0; --b) {
        int c = hist[b];
        if (cum + c >= remaining) break;
        cum += c;
      }
      bsel[0] = b;
      bsel[1] = cum;
    }
    __syncthreads();
    pval |= ((unsigned)bsel[0]) << shift;
    remaining -= bsel[1];
    __syncthreads();
  }
  const float Tval = unkey(pval);
  // |float(g16) - g_blas| <= e ~ 2.5e-3; DELTA >= 2e required, 6e-3 margin.
  const float DELTA = 6e-3f;

  // classification: thread t owns word t; XOR-permuted read order so lane
  // banks are distinct (removes 64-way conflict of the linear order).
  unsigned word = 0;
  for (int j = 0; j < 32; ++j) {
    const int jb = j ^ (tid & 31);
    const int h = tid * 32 + jb;
    const float v = gv[h];
    if (v > Tval + DELTA) {
      word |= 1u << jb;
    } else if (v >= Tval - DELTA) {
      int c = atomicAdd(&cnt[0], 1);
      if (c < NCAND) cidx[c] = h;
    }
  }
  bmap[tid] = word;
  atomicAdd(&cnt[1], __popc(word));
  __syncthreads();

  const int m = min(cnt[0], NCAND);
  const int need = max(K - cnt[1], 0);
  const float* xrow = X + (size_t)r * DMODEL;

  // segment-parallel BLAS-emulated dots (bit-identical to blas_emu_dot):
  // 7 threads per candidate, one kc=320 sequential-FMA chain each; partials
  // combined ascending with __fadd_rn.
  for (int t = tid; t < m * NSEG; t += 256) {
    const int c = t / NSEG, s = t - (t / NSEG) * NSEG;
    const int kb = s * BLAS_KC;
    const int ke = (kb + BLAS_KC < DMODEL) ? kb + BLAS_KC : DMODEL;
    const float* wrow = Wg + (size_t)cidx[c] * DMODEL;
    float acc = 0.0f;
    for (int k = kb; k < ke; ++k)
      acc = __builtin_fmaf(xrow[k], wrow[k], acc);
    cpart[c][s] = acc;
  }
  __syncthreads();
  for (int c = tid; c < m; c += 256) {
    float ctot = cpart[c][0];
#pragma unroll
    for (int s = 1; s < NSEG; ++s) ctot = __fadd_rn(ctot, cpart[c][s]);
    cval[c] = ctot;
  }
  __syncthreads();

  // pick top `need` among candidates by (emulated value desc, index asc)
  if (tid == 0) {
    for (int s = 0; s < need; ++s) {
      int best = -1;
      float bv = 0.0f;
      int bix = 0x7fffffff;
      for (int c = 0; c < m; ++c) {
        float v = cval[c];
        if (v <= -1.0e29f) continue;
        if (best < 0 || v > bv || (v == bv && cidx[c] < bix)) {
          bv = v; bix = cidx[c]; best = c;
        }
      }
      if (best < 0) break;
      atomicOr(&bmap[cidx[best] >> 5], 1u << (cidx[best] & 31));
      cval[best] = -1.0e30f;
    }
  }
  __syncthreads();
  Mask[(size_t)r * (H / 32) + tid] = bmap[tid];
}

// ---------------- mask + silu in-place on Hid (swizzled layout) -------------
__global__ __launch_bounds__(256)
void mask_silu(f16* __restrict__ P, const f16* __restrict__ G16,
               const unsigned* __restrict__ Msk, int n8) {
  const int stride = gridDim.x * blockDim.x;
  for (int i = blockIdx.x * blockDim.x + threadIdx.x; i < n8; i += stride) {
    const int row = i >> 10;
    const int gi = i & 1023;
    const int ls = (gi & 7) ^ (row & 7);
    const int c8l = ((gi >> 3) << 6) | (ls << 3);
    const unsigned mw = Msk[((size_t)row << 8) + (c8l >> 5)];
    const unsigned bits = (mw >> (c8l & 31)) & 0xFFu;
    half8v h = reinterpret_cast<half8v*>(P)[i];
    half8v g = reinterpret_cast<const half8v*>(G16)[i];
    half8v o;
#pragma unroll
    for (int j = 0; j < 8; ++j) {
      float gg = (float)g[j];
      float act = gg / (1.0f + __expf(-gg));
      o[j] = ((bits >> j) & 1u) ? (f16)((float)h[j] * act) : (f16)0.0f;
    }
    reinterpret_cast<half8v*>(P)[i] = o;
  }
}

// ---------------- down GEMM: out = p @ w_down^T (both f16, swizzled) --------
__global__ __launch_bounds__(256, 2)
void gemm_down(const f16* __restrict__ A, const f16* __restrict__ B16,
               float* __restrict__ C) {
  __shared__ f16 As[128 * 64];
  __shared__ f16 Bs[128 * 64];
  const int nwg = gridDim.x;
  const int bid = blockIdx.x;
  const int wg = (bid & 7) * (nwg >> 3) + (bid >> 3);
  const int NT = DMODEL >> 7;
  const int bm = wg / NT, bn = wg % NT;
  const int tid = threadIdx.x;
  const int w = tid >> 6, l = tid & 63;
  const int wr = w >> 1, wc = w & 1;
  const int lr = l >> 3, lc8 = (l & 7) << 3;

  f32x4 acc[4][4] = {};

  for (int kt = 0; kt < HIDDEN; kt += 64) {
    __syncthreads();
#pragma unroll
    for (int i = 0; i < 4; ++i) {
      const int row = i * 32 + w * 8;
      gload_lds16(A + (size_t)(bm * 128 + row + lr) * HIDDEN + kt + lc8, &As[row * 64]);
      gload_lds16(B16 + (size_t)(bn * 128 + row + lr) * HIDDEN + kt + lc8, &Bs[row * 64]);
    }
    __syncthreads();
#pragma unroll
    for (int ks = 0; ks < 2; ++ks) {
      half8v af[4], bf[4];
#pragma unroll
      for (int mf = 0; mf < 4; ++mf)
        af[mf] = frag_read(As, wr * 64 + mf * 16 + (l & 15), ks, l);
#pragma unroll
      for (int nf = 0; nf < 4; ++nf)
        bf[nf] = frag_read(Bs, wc * 64 + nf * 16 + (l & 15), ks, l);
#pragma unroll
      for (int mf = 0; mf < 4; ++mf)
#pragma unroll
        for (int nf = 0; nf < 4; ++nf)
          acc[mf][nf] = __builtin_amdgcn_mfma_f32_16x16x32_f16(af[mf], bf[nf], acc[mf][nf], 0, 0, 0);
    }
  }

  const int row0 = bm * 128 + wr * 64 + (l >> 4) * 4;
  const int col0 = bn * 128 + wc * 64 + (l & 15);
#pragma unroll
  for (int mf = 0; mf < 4; ++mf)
#pragma unroll
    for (int nf = 0; nf < 4; ++nf)
#pragma unroll
      for (int j = 0; j < 4; ++j)
        C[(size_t)(row0 + mf * 16 + j) * DMODEL + (col0 + nf * 16)] = acc[mf][nf][j];
}

// ---------------- launch ----------------
extern "C" void kernel_launch(void* const* d_in, const int* in_sizes, int n_in,
                              void* d_out, int out_size, void* d_ws, size_t ws_size,
                              hipStream_t stream) {
  const float* x = (const float*)d_in[0];
  const float* w_up = (const float*)d_in[1];
  const float* w_gate = (const float*)d_in[2];
  const float* w_down = (const float*)d_in[3];
  float* out = (float*)d_out;

  const size_t g_bytes = (size_t)NTOK * HIDDEN * 2;
  const size_t p_bytes = (size_t)NTOK * HIDDEN * 2;
  const size_t m_bytes = (size_t)NTOK * (HIDDEN / 32) * 4;
  const size_t x16_b = (size_t)NTOK * DMODEL * 2;
  const size_t wg16_b = (size_t)HIDDEN * DMODEL * 2;
  const size_t wu16_b = (size_t)HIDDEN * DMODEL * 2;
  const size_t wd16_b = (size_t)DMODEL * HIDDEN * 2;
  if (ws_size < g_bytes + p_bytes + m_bytes + x16_b + wg16_b + wu16_b + wd16_b) {
    hipMemsetAsync(d_out, 0, (size_t)out_size * 4, stream);
    return;
  }

  char* p = (char*)d_ws;
  f16* g16 = (f16*)p;       p += g_bytes;
  f16* pbuf = (f16*)p;      p += p_bytes;
  unsigned* msk = (unsigned*)p; p += m_bytes;
  f16* x16 = (f16*)p;       p += x16_b;
  f16* wg16 = (f16*)p;      p += wg16_b;
  f16* wu16 = (f16*)p;      p += wu16_b;
  f16* wd16 = (f16*)p;

  dim3 blk(256);

  cast_swz<<<2048, blk, 0, stream>>>(x, x16, DMODEL, NTOK * DMODEL / 8);
  cast_swz<<<2048, blk, 0, stream>>>(w_gate, wg16, DMODEL, HIDDEN * DMODEL / 8);
  cast_swz<<<2048, blk, 0, stream>>>(w_up, wu16, DMODEL, HIDDEN * DMODEL / 8);
  cast_swz<<<2048, blk, 0, stream>>>(w_down, wd16, HIDDEN, DMODEL * HIDDEN / 8);

  gemm_upgate<<<(NTOK / 128) * (HIDDEN / 128), blk, 0, stream>>>(
      x16, wg16, wu16, g16, pbuf);

  topk_mask<<<NTOK, blk, 0, stream>>>(g16, x, w_gate, msk, HIDDEN, TOPK_K);

  mask_silu<<<2048, blk, 0, stream>>>(pbuf, g16, msk, NTOK * HIDDEN / 8);

  gemm_down<<<(NTOK / 128) * (DMODEL / 128), blk, 0, stream>>>(pbuf, wd16, out);
}

// Round 14
// 1249.847 us; speedup vs baseline: 1.4308x; 1.4189x over previous
//
#include <hip/hip_runtime.h>
#include <cstdint>
#include <cstddef>

#define NTOK 4096
#define DMODEL 2048
#define HIDDEN 8192
#define TOPK_K 1024
#define NCAND 128
#define BLAS_KC 320   // OpenBLAS SGEMM_DEFAULT_Q (SKX route) -- verified round 7
#define NSEG 7        // ceil(2048/320): segments of the BLAS accumulation chain

typedef __fp16 f16;
typedef __fp16 half8v __attribute__((ext_vector_type(8)));
typedef float f32x4 __attribute__((ext_vector_type(4)));

__device__ __forceinline__ void gload_lds16(const void* gptr, void* lptr) {
  __builtin_amdgcn_global_load_lds(
      (const __attribute__((address_space(1))) void*)gptr,
      (__attribute__((address_space(3))) void*)lptr, 16, 0, 0);
}

__device__ __forceinline__ unsigned sortable_key(float f) {
  unsigned u = __float_as_uint(f);
  return (u >> 31) ? ~u : (u | 0x80000000u);
}
__device__ __forceinline__ float unkey(unsigned k) {
  unsigned u = (k & 0x80000000u) ? (k ^ 0x80000000u) : ~k;
  return __uint_as_float(u);
}

// ---- Global+LDS swizzle convention (T2): within each (row, 64-col block),
// logical 16B slot q lives at physical slot q ^ (row & 7).
__device__ __forceinline__ half8v frag_read(const f16* __restrict__ lds, int R,
                                            int ks, int l) {
  return *reinterpret_cast<const half8v*>(
      &lds[R * 64 + ((((ks * 4) + (l >> 4)) ^ (l & 7)) * 8)]);
}

// ---------------- cast fp32 -> f16 with swizzled layout ---------------------
__global__ __launch_bounds__(256)
void cast_swz(const float* __restrict__ in, f16* __restrict__ out, int K, int n8) {
  const int stride = gridDim.x * blockDim.x;
  const int gpr = K >> 3;
  for (int i = blockIdx.x * blockDim.x + threadIdx.x; i < n8; i += stride) {
    const int row = i / gpr;
    const int gi = i - row * gpr;
    const int cb = (gi >> 3) << 6;
    const int ps = (gi & 7) ^ (row & 7);
    const float* s = in + (size_t)row * K + cb + ((gi & 7) << 3);
    float4 v0 = *reinterpret_cast<const float4*>(s);
    float4 v1 = *reinterpret_cast<const float4*>(s + 4);
    half8v h = {(f16)v0.x, (f16)v0.y, (f16)v0.z, (f16)v0.w,
                (f16)v1.x, (f16)v1.y, (f16)v1.z, (f16)v1.w};
    *reinterpret_cast<half8v*>(out + (size_t)row * K + cb + (ps << 3)) = h;
  }
}

// ---------------- fused up+gate GEMM (f16 operands, gload_lds staging) ------
__global__ __launch_bounds__(256, 2)
void gemm_upgate(const f16* __restrict__ X16, const f16* __restrict__ Wg16,
                 const f16* __restrict__ Wu16, f16* __restrict__ G16,
                 f16* __restrict__ Hid) {
  __shared__ f16 As[128 * 64];
  __shared__ f16 Bgs[128 * 64];
  __shared__ f16 Bus[128 * 64];
  const int nwg = gridDim.x;
  const int bid = blockIdx.x;
  const int wg = (bid & 7) * (nwg >> 3) + (bid >> 3);
  const int NT = HIDDEN >> 7;
  const int bm = wg / NT, bn = wg % NT;
  const int tid = threadIdx.x;
  const int w = tid >> 6, l = tid & 63;
  const int wr = w >> 1, wc = w & 1;
  const int lr = l >> 3, lc8 = (l & 7) << 3;

  f32x4 accg[4][4] = {};
  f32x4 accu[4][4] = {};

  for (int kt = 0; kt < DMODEL; kt += 64) {
    __syncthreads();
#pragma unroll
    for (int i = 0; i < 4; ++i) {
      const int row = i * 32 + w * 8;
      gload_lds16(X16 + (size_t)(bm * 128 + row + lr) * DMODEL + kt + lc8, &As[row * 64]);
      gload_lds16(Wg16 + (size_t)(bn * 128 + row + lr) * DMODEL + kt + lc8, &Bgs[row * 64]);
      gload_lds16(Wu16 + (size_t)(bn * 128 + row + lr) * DMODEL + kt + lc8, &Bus[row * 64]);
    }
    __syncthreads();
#pragma unroll
    for (int ks = 0; ks < 2; ++ks) {
      half8v af[4], bg[4], bu[4];
#pragma unroll
      for (int mf = 0; mf < 4; ++mf)
        af[mf] = frag_read(As, wr * 64 + mf * 16 + (l & 15), ks, l);
#pragma unroll
      for (int nf = 0; nf < 4; ++nf) {
        bg[nf] = frag_read(Bgs, wc * 64 + nf * 16 + (l & 15), ks, l);
        bu[nf] = frag_read(Bus, wc * 64 + nf * 16 + (l & 15), ks, l);
      }
#pragma unroll
      for (int mf = 0; mf < 4; ++mf)
#pragma unroll
        for (int nf = 0; nf < 4; ++nf) {
          accg[mf][nf] = __builtin_amdgcn_mfma_f32_16x16x32_f16(af[mf], bg[nf], accg[mf][nf], 0, 0, 0);
          accu[mf][nf] = __builtin_amdgcn_mfma_f32_16x16x32_f16(af[mf], bu[nf], accu[mf][nf], 0, 0, 0);
        }
    }
  }

  const int row0 = bm * 128 + wr * 64 + (l >> 4) * 4;
  const int col0 = bn * 128 + wc * 64 + (l & 15);
#pragma unroll
  for (int mf = 0; mf < 4; ++mf)
#pragma unroll
    for (int nf = 0; nf < 4; ++nf)
#pragma unroll
      for (int j = 0; j < 4; ++j) {
        const int rr = row0 + mf * 16 + j;
        const int cc = col0 + nf * 16;
        const int pcc = (cc & ~63) | (cc & 7) | (((((cc >> 3) & 7) ^ (rr & 7))) << 3);
        const size_t idx = (size_t)rr * HIDDEN + pcc;
        G16[idx] = (f16)accg[mf][nf][j];
        Hid[idx] = (f16)accu[mf][nf][j];
      }
}

// ---------------- top-k -> bitmap -------------------------------------------
// Round-9/13-proven 4-pass radix with three latency fixes, all
// semantics-preserving (Tval/candidate set bit-identical):
//   (1) keys staged once as u32 (passes + classification in key space);
//   (2) branchless full-256 tid0 bucket scan (loads pipeline, no break);
//   (3) float4 loads in the segment-parallel BLAS dots (same FMA chain).
__global__ __launch_bounds__(256)
void topk_mask(const f16* __restrict__ G16, const float* __restrict__ X,
               const float* __restrict__ Wg, unsigned* __restrict__ Mask,
               int H, int K) {
  __shared__ unsigned kv[HIDDEN];        // 32 KB sortable keys, logical order
  __shared__ int hist[256];
  __shared__ int bsel[2];
  __shared__ unsigned bmap[HIDDEN / 32];
  __shared__ int cnt[2];
  __shared__ int cidx[NCAND];
  __shared__ float cpart[NCAND][NSEG];
  __shared__ float cval[NCAND];
  const int r = blockIdx.x;
  const int tid = threadIdx.x;
  const f16* grow = G16 + (size_t)r * H;

  // stage u32 sortable keys (unswizzle the G16 layout)
  for (int i = tid; i < H / 8; i += 256) {
    half8v v = reinterpret_cast<const half8v*>(grow)[i];
    const int ls = (i & 7) ^ (r & 7);
    const int c8l = ((i >> 3) << 6) | (ls << 3);
#pragma unroll
    for (int j = 0; j < 8; ++j) kv[c8l + j] = sortable_key((float)v[j]);
  }
  if (tid < 2) cnt[tid] = 0;
  __syncthreads();

  // 4-pass radix select of k-th largest (same selection math as r9/r13)
  unsigned pval = 0;
  int remaining = K;
  for (int pass = 0; pass < 4; ++pass) {
    const int shift = 24 - pass * 8;
    const unsigned pmask = (pass == 0) ? 0u : (0xFFFFFFFFu << (32 - 8 * pass));
    hist[tid] = 0;
    __syncthreads();
    for (int i = tid; i < H; i += 256) {
      unsigned kk = kv[i];
      if ((kk & pmask) == pval) atomicAdd(&hist[(kk >> shift) & 255], 1);
    }
    __syncthreads();
    if (tid == 0) {
      // branchless full scan: same result as the r9 break-loop
      int cum = 0, sel = 0, selcum = 0, found = 0;
      for (int b = 255; b > 0; --b) {
        int c = hist[b];
        if (!found && cum + c >= remaining) { sel = b; selcum = cum; found = 1; }
        cum += c;
      }
      if (!found) selcum = cum;
      bsel[0] = sel;
      bsel[1] = selcum;
    }
    __syncthreads();
    pval |= ((unsigned)bsel[0]) << shift;
    remaining -= bsel[1];
    __syncthreads();
  }
  const float Tval = unkey(pval);
  // |float(g16) - g_blas| <= e ~ 2.5e-3; DELTA >= 2e required, 6e-3 margin.
  const float DELTA = 6e-3f;
  const unsigned keyHi = sortable_key(Tval + DELTA);  // v > Tval+DELTA <=> kk > keyHi
  const unsigned keyLo = sortable_key(Tval - DELTA);  // v >= Tval-DELTA <=> kk >= keyLo

  // classification in key space; XOR-permuted order (bank-conflict-free)
  unsigned word = 0;
  for (int j = 0; j < 32; ++j) {
    const int jb = j ^ (tid & 31);
    const int h = tid * 32 + jb;
    const unsigned kk = kv[h];
    if (kk > keyHi) {
      word |= 1u << jb;
    } else if (kk >= keyLo) {
      int c = atomicAdd(&cnt[0], 1);
      if (c < NCAND) cidx[c] = h;
    }
  }
  bmap[tid] = word;
  atomicAdd(&cnt[1], __popc(word));
  __syncthreads();

  const int m = min(cnt[0], NCAND);
  const int need = max(K - cnt[1], 0);
  const float* xrow = X + (size_t)r * DMODEL;

  // segment-parallel BLAS-emulated dots (bit-identical chain to blas_emu_dot):
  // 7 threads per candidate, one kc=320 k-ascending FMA chain each; float4
  // loads (chain order unchanged); partials combined ascending with __fadd_rn.
  for (int t = tid; t < m * NSEG; t += 256) {
    const int c = t / NSEG, s = t - (t / NSEG) * NSEG;
    const int kb = s * BLAS_KC;
    const int ke = (kb + BLAS_KC < DMODEL) ? kb + BLAS_KC : DMODEL;
    const float* wrow = Wg + (size_t)cidx[c] * DMODEL;
    const float4* xv = reinterpret_cast<const float4*>(xrow + kb);
    const float4* wv = reinterpret_cast<const float4*>(wrow + kb);
    float acc = 0.0f;
    const int nq = (ke - kb) >> 2;
    for (int q = 0; q < nq; ++q) {
      float4 a = xv[q], b = wv[q];
      acc = __builtin_fmaf(a.x, b.x, acc);
      acc = __builtin_fmaf(a.y, b.y, acc);
      acc = __builtin_fmaf(a.z, b.z, acc);
      acc = __builtin_fmaf(a.w, b.w, acc);
    }
    cpart[c][s] = acc;
  }
  __syncthreads();
  for (int c = tid; c < m; c += 256) {
    float ctot = cpart[c][0];
#pragma unroll
    for (int s = 1; s < NSEG; ++s) ctot = __fadd_rn(ctot, cpart[c][s]);
    cval[c] = ctot;
  }
  __syncthreads();

  // pick top `need` among candidates by (emulated value desc, index asc)
  if (tid == 0) {
    for (int s = 0; s < need; ++s) {
      int best = -1;
      float bv = 0.0f;
      int bix = 0x7fffffff;
      for (int c = 0; c < m; ++c) {
        float v = cval[c];
        if (v <= -1.0e29f) continue;
        if (best < 0 || v > bv || (v == bv && cidx[c] < bix)) {
          bv = v; bix = cidx[c]; best = c;
        }
      }
      if (best < 0) break;
      atomicOr(&bmap[cidx[best] >> 5], 1u << (cidx[best] & 31));
      cval[best] = -1.0e30f;
    }
  }
  __syncthreads();
  Mask[(size_t)r * (H / 32) + tid] = bmap[tid];
}

// ---------------- mask + silu in-place on Hid (swizzled layout) -------------
__global__ __launch_bounds__(256)
void mask_silu(f16* __restrict__ P, const f16* __restrict__ G16,
               const unsigned* __restrict__ Msk, int n8) {
  const int stride = gridDim.x * blockDim.x;
  for (int i = blockIdx.x * blockDim.x + threadIdx.x; i < n8; i += stride) {
    const int row = i >> 10;
    const int gi = i & 1023;
    const int ls = (gi & 7) ^ (row & 7);
    const int c8l = ((gi >> 3) << 6) | (ls << 3);
    const unsigned mw = Msk[((size_t)row << 8) + (c8l >> 5)];
    const unsigned bits = (mw >> (c8l & 31)) & 0xFFu;
    half8v h = reinterpret_cast<half8v*>(P)[i];
    half8v g = reinterpret_cast<const half8v*>(G16)[i];
    half8v o;
#pragma unroll
    for (int j = 0; j < 8; ++j) {
      float gg = (float)g[j];
      float act = gg / (1.0f + __expf(-gg));
      o[j] = ((bits >> j) & 1u) ? (f16)((float)h[j] * act) : (f16)0.0f;
    }
    reinterpret_cast<half8v*>(P)[i] = o;
  }
}

// ---------------- down GEMM: out = p @ w_down^T (both f16, swizzled) --------
__global__ __launch_bounds__(256, 2)
void gemm_down(const f16* __restrict__ A, const f16* __restrict__ B16,
               float* __restrict__ C) {
  __shared__ f16 As[128 * 64];
  __shared__ f16 Bs[128 * 64];
  const int nwg = gridDim.x;
  const int bid = blockIdx.x;
  const int wg = (bid & 7) * (nwg >> 3) + (bid >> 3);
  const int NT = DMODEL >> 7;
  const int bm = wg / NT, bn = wg % NT;
  const int tid = threadIdx.x;
  const int w = tid >> 6, l = tid & 63;
  const int wr = w >> 1, wc = w & 1;
  const int lr = l >> 3, lc8 = (l & 7) << 3;

  f32x4 acc[4][4] = {};

  for (int kt = 0; kt < HIDDEN; kt += 64) {
    __syncthreads();
#pragma unroll
    for (int i = 0; i < 4; ++i) {
      const int row = i * 32 + w * 8;
      gload_lds16(A + (size_t)(bm * 128 + row + lr) * HIDDEN + kt + lc8, &As[row * 64]);
      gload_lds16(B16 + (size_t)(bn * 128 + row + lr) * HIDDEN + kt + lc8, &Bs[row * 64]);
    }
    __syncthreads();
#pragma unroll
    for (int ks = 0; ks < 2; ++ks) {
      half8v af[4], bf[4];
#pragma unroll
      for (int mf = 0; mf < 4; ++mf)
        af[mf] = frag_read(As, wr * 64 + mf * 16 + (l & 15), ks, l);
#pragma unroll
      for (int nf = 0; nf < 4; ++nf)
        bf[nf] = frag_read(Bs, wc * 64 + nf * 16 + (l & 15), ks, l);
#pragma unroll
      for (int mf = 0; mf < 4; ++mf)
#pragma unroll
        for (int nf = 0; nf < 4; ++nf)
          acc[mf][nf] = __builtin_amdgcn_mfma_f32_16x16x32_f16(af[mf], bf[nf], acc[mf][nf], 0, 0, 0);
    }
  }

  const int row0 = bm * 128 + wr * 64 + (l >> 4) * 4;
  const int col0 = bn * 128 + wc * 64 + (l & 15);
#pragma unroll
  for (int mf = 0; mf < 4; ++mf)
#pragma unroll
    for (int nf = 0; nf < 4; ++nf)
#pragma unroll
      for (int j = 0; j < 4; ++j)
        C[(size_t)(row0 + mf * 16 + j) * DMODEL + (col0 + nf * 16)] = acc[mf][nf][j];
}

// ---------------- launch ----------------
extern "C" void kernel_launch(void* const* d_in, const int* in_sizes, int n_in,
                              void* d_out, int out_size, void* d_ws, size_t ws_size,
                              hipStream_t stream) {
  const float* x = (const float*)d_in[0];
  const float* w_up = (const float*)d_in[1];
  const float* w_gate = (const float*)d_in[2];
  const float* w_down = (const float*)d_in[3];
  float* out = (float*)d_out;

  const size_t g_bytes = (size_t)NTOK * HIDDEN * 2;
  const size_t p_bytes = (size_t)NTOK * HIDDEN * 2;
  const size_t m_bytes = (size_t)NTOK * (HIDDEN / 32) * 4;
  const size_t x16_b = (size_t)NTOK * DMODEL * 2;
  const size_t wg16_b = (size_t)HIDDEN * DMODEL * 2;
  const size_t wu16_b = (size_t)HIDDEN * DMODEL * 2;
  const size_t wd16_b = (size_t)DMODEL * HIDDEN * 2;
  if (ws_size < g_bytes + p_bytes + m_bytes + x16_b + wg16_b + wu16_b + wd16_b) {
    hipMemsetAsync(d_out, 0, (size_t)out_size * 4, stream);
    return;
  }

  char* p = (char*)d_ws;
  f16* g16 = (f16*)p;       p += g_bytes;
  f16* pbuf = (f16*)p;      p += p_bytes;
  unsigned* msk = (unsigned*)p; p += m_bytes;
  f16* x16 = (f16*)p;       p += x16_b;
  f16* wg16 = (f16*)p;      p += wg16_b;
  f16* wu16 = (f16*)p;      p += wu16_b;
  f16* wd16 = (f16*)p;

  dim3 blk(256);

  cast_swz<<<2048, blk, 0, stream>>>(x, x16, DMODEL, NTOK * DMODEL / 8);
  cast_swz<<<2048, blk, 0, stream>>>(w_gate, wg16, DMODEL, HIDDEN * DMODEL / 8);
  cast_swz<<<2048, blk, 0, stream>>>(w_up, wu16, DMODEL, HIDDEN * DMODEL / 8);
  cast_swz<<<2048, blk, 0, stream>>>(w_down, wd16, HIDDEN, DMODEL * HIDDEN / 8);

  gemm_upgate<<<(NTOK / 128) * (HIDDEN / 128), blk, 0, stream>>>(
      x16, wg16, wu16, g16, pbuf);

  topk_mask<<<NTOK, blk, 0, stream>>>(g16, x, w_gate, msk, HIDDEN, TOPK_K);

  mask_silu<<<2048, blk, 0, stream>>>(pbuf, g16, msk, NTOK * HIDDEN / 8);

  gemm_down<<<(NTOK / 128) * (DMODEL / 128), blk, 0, stream>>>(pbuf, wd16, out);
}

// Round 15
// 1002.051 us; speedup vs baseline: 1.7847x; 1.2473x over previous
//
#include <hip/hip_runtime.h>
#include <cstdint>
#include <cstddef>

#define NTOK 4096
#define DMODEL 2048
#define HIDDEN 8192
#define TOPK_K 1024
#define NCAND 128
#define BLAS_KC 320   // OpenBLAS SGEMM_DEFAULT_Q (SKX route) -- verified round 7
#define NSEG 7        // ceil(2048/320): segments of the BLAS accumulation chain

typedef __fp16 f16;
typedef __fp16 half8v __attribute__((ext_vector_type(8)));
typedef float f32x4 __attribute__((ext_vector_type(4)));

__device__ __forceinline__ void gload_lds16(const void* gptr, void* lptr) {
  __builtin_amdgcn_global_load_lds(
      (const __attribute__((address_space(1))) void*)gptr,
      (__attribute__((address_space(3))) void*)lptr, 16, 0, 0);
}

__device__ __forceinline__ unsigned sortable_key(float f) {
  unsigned u = __float_as_uint(f);
  return (u >> 31) ? ~u : (u | 0x80000000u);
}
__device__ __forceinline__ float unkey(unsigned k) {
  unsigned u = (k & 0x80000000u) ? (k ^ 0x80000000u) : ~k;
  return __uint_as_float(u);
}

// ---- Global+LDS swizzle convention (T2): within each (row, 64-col block),
// logical 16B slot q lives at physical slot q ^ (row & 7).
__device__ __forceinline__ half8v frag_read(const f16* __restrict__ lds, int R,
                                            int ks, int l) {
  return *reinterpret_cast<const half8v*>(
      &lds[R * 64 + ((((ks * 4) + (l >> 4)) ^ (l & 7)) * 8)]);
}

// ---------------- cast fp32 -> f16 with swizzled layout ---------------------
__global__ __launch_bounds__(256)
void cast_swz(const float* __restrict__ in, f16* __restrict__ out, int K, int n8) {
  const int stride = gridDim.x * blockDim.x;
  const int gpr = K >> 3;
  for (int i = blockIdx.x * blockDim.x + threadIdx.x; i < n8; i += stride) {
    const int row = i / gpr;
    const int gi = i - row * gpr;
    const int cb = (gi >> 3) << 6;
    const int ps = (gi & 7) ^ (row & 7);
    const float* s = in + (size_t)row * K + cb + ((gi & 7) << 3);
    float4 v0 = *reinterpret_cast<const float4*>(s);
    float4 v1 = *reinterpret_cast<const float4*>(s + 4);
    half8v h = {(f16)v0.x, (f16)v0.y, (f16)v0.z, (f16)v0.w,
                (f16)v1.x, (f16)v1.y, (f16)v1.z, (f16)v1.w};
    *reinterpret_cast<half8v*>(out + (size_t)row * K + cb + (ps << 3)) = h;
  }
}

// ---------------- fused up+gate GEMM (f16 operands, gload_lds staging) ------
__global__ __launch_bounds__(256, 2)
void gemm_upgate(const f16* __restrict__ X16, const f16* __restrict__ Wg16,
                 const f16* __restrict__ Wu16, f16* __restrict__ G16,
                 f16* __restrict__ Hid) {
  __shared__ f16 As[128 * 64];
  __shared__ f16 Bgs[128 * 64];
  __shared__ f16 Bus[128 * 64];
  const int nwg = gridDim.x;
  const int bid = blockIdx.x;
  const int wg = (bid & 7) * (nwg >> 3) + (bid >> 3);
  const int NT = HIDDEN >> 7;
  const int bm = wg / NT, bn = wg % NT;
  const int tid = threadIdx.x;
  const int w = tid >> 6, l = tid & 63;
  const int wr = w >> 1, wc = w & 1;
  const int lr = l >> 3, lc8 = (l & 7) << 3;

  f32x4 accg[4][4] = {};
  f32x4 accu[4][4] = {};

  for (int kt = 0; kt < DMODEL; kt += 64) {
    __syncthreads();
#pragma unroll
    for (int i = 0; i < 4; ++i) {
      const int row = i * 32 + w * 8;
      gload_lds16(X16 + (size_t)(bm * 128 + row + lr) * DMODEL + kt + lc8, &As[row * 64]);
      gload_lds16(Wg16 + (size_t)(bn * 128 + row + lr) * DMODEL + kt + lc8, &Bgs[row * 64]);
      gload_lds16(Wu16 + (size_t)(bn * 128 + row + lr) * DMODEL + kt + lc8, &Bus[row * 64]);
    }
    __syncthreads();
#pragma unroll
    for (int ks = 0; ks < 2; ++ks) {
      half8v af[4], bg[4], bu[4];
#pragma unroll
      for (int mf = 0; mf < 4; ++mf)
        af[mf] = frag_read(As, wr * 64 + mf * 16 + (l & 15), ks, l);
#pragma unroll
      for (int nf = 0; nf < 4; ++nf) {
        bg[nf] = frag_read(Bgs, wc * 64 + nf * 16 + (l & 15), ks, l);
        bu[nf] = frag_read(Bus, wc * 64 + nf * 16 + (l & 15), ks, l);
      }
#pragma unroll
      for (int mf = 0; mf < 4; ++mf)
#pragma unroll
        for (int nf = 0; nf < 4; ++nf) {
          accg[mf][nf] = __builtin_amdgcn_mfma_f32_16x16x32_f16(af[mf], bg[nf], accg[mf][nf], 0, 0, 0);
          accu[mf][nf] = __builtin_amdgcn_mfma_f32_16x16x32_f16(af[mf], bu[nf], accu[mf][nf], 0, 0, 0);
        }
    }
  }

  const int row0 = bm * 128 + wr * 64 + (l >> 4) * 4;
  const int col0 = bn * 128 + wc * 64 + (l & 15);
#pragma unroll
  for (int mf = 0; mf < 4; ++mf)
#pragma unroll
    for (int nf = 0; nf < 4; ++nf)
#pragma unroll
      for (int j = 0; j < 4; ++j) {
        const int rr = row0 + mf * 16 + j;
        const int cc = col0 + nf * 16;
        const int pcc = (cc & ~63) | (cc & 7) | (((((cc >> 3) & 7) ^ (rr & 7))) << 3);
        const size_t idx = (size_t)rr * HIDDEN + pcc;
        G16[idx] = (f16)accg[mf][nf][j];
        Hid[idx] = (f16)accu[mf][nf][j];
      }
}

// ---------------- top-k -> bitmap -------------------------------------------
// Structural change vs r14: NO key LDS cache -- each sweep re-reads the L2-hot
// g16 row (16 KB) and re-keys on the fly. LDS drops 39.9KB -> ~6.7KB, so
// occupancy goes 4 -> 8 blocks/CU (wave-limited). Semantics bit-identical:
//   * 3 radix passes (byte0 is sign-determined for fp16-exact floats:
//     low 13 key bits are 0x0000/0x1FFF -> kT identical to 4-pass);
//   * parallel rank selection == serial (val desc, idx asc) pick set;
//   * candidate dots verbatim from r14 (bit-exact BLAS chains).
__global__ __launch_bounds__(256)
void topk_mask(const f16* __restrict__ G16, const float* __restrict__ X,
               const float* __restrict__ Wg, unsigned* __restrict__ Mask,
               int H, int K) {
  __shared__ int hist[256];
  __shared__ int bsel[2];
  __shared__ unsigned bmap[HIDDEN / 32];
  __shared__ int cnt[2];
  __shared__ int cidx[NCAND];
  __shared__ float cpart[NCAND][NSEG];
  __shared__ float cval[NCAND];
  const int r = blockIdx.x;
  const int tid = threadIdx.x;
  const f16* grow = G16 + (size_t)r * H;
  if (tid < 2) cnt[tid] = 0;

  // 3-pass radix select of k-th largest (re-reads g16 each pass; L2-hot)
  unsigned pval = 0;
  int remaining = K;
  for (int pass = 0; pass < 3; ++pass) {
    const int shift = 24 - pass * 8;
    const unsigned pmask = (pass == 0) ? 0u : (0xFFFFFFFFu << (32 - 8 * pass));
    hist[tid] = 0;
    __syncthreads();
    for (int i = tid; i < H / 8; i += 256) {
      half8v v = reinterpret_cast<const half8v*>(grow)[i];
#pragma unroll
      for (int j = 0; j < 8; ++j) {
        unsigned kk = sortable_key((float)v[j]);
        if ((kk & pmask) == pval) atomicAdd(&hist[(kk >> shift) & 255], 1);
      }
    }
    __syncthreads();
    if (tid == 0) {
      int cum = 0, sel = 0, selcum = 0, found = 0;
      for (int b = 255; b > 0; --b) {
        int c = hist[b];
        if (!found && cum + c >= remaining) { sel = b; selcum = cum; found = 1; }
        cum += c;
      }
      if (!found) selcum = cum;
      bsel[0] = sel;
      bsel[1] = selcum;
    }
    __syncthreads();
    pval |= ((unsigned)bsel[0]) << shift;
    remaining -= bsel[1];
    __syncthreads();
  }
  // byte0 is sign-determined: fp16-exact floats have zero low-13 mantissa key
  // bits -> key byte0 = 0x00 for non-negative (key bit31=1), 0xFF for negative.
  const unsigned kT = pval | ((pval & 0x80000000u) ? 0x00u : 0xFFu);
  const float Tval = unkey(kT);
  // |float(g16) - g_blas| <= e ~ 2.5e-3; DELTA >= 2e required, 6e-3 margin.
  const float DELTA = 6e-3f;
  const unsigned keyHi = sortable_key(Tval + DELTA);  // v > Tval+DELTA <=> kk > keyHi
  const unsigned keyLo = sortable_key(Tval - DELTA);  // v >= Tval-DELTA <=> kk >= keyLo

  // classification: thread t owns logical elements [t*32, t*32+32) -> word t
  unsigned word = 0;
#pragma unroll
  for (int q = 0; q < 4; ++q) {
    const int gl = tid * 4 + q;                        // logical 8-group
    const int gp = (gl & ~7) | ((gl & 7) ^ (r & 7));   // physical (swizzled)
    half8v v = reinterpret_cast<const half8v*>(grow)[gp];
#pragma unroll
    for (int j = 0; j < 8; ++j) {
      unsigned kk = sortable_key((float)v[j]);
      const int bit = q * 8 + j;
      if (kk > keyHi) {
        word |= 1u << bit;
      } else if (kk >= keyLo) {
        int c = atomicAdd(&cnt[0], 1);
        if (c < NCAND) cidx[c] = tid * 32 + bit;
      }
    }
  }
  bmap[tid] = word;
  atomicAdd(&cnt[1], __popc(word));
  __syncthreads();

  const int m = min(cnt[0], NCAND);
  const int need = max(K - cnt[1], 0);
  const float* xrow = X + (size_t)r * DMODEL;

  // segment-parallel BLAS-emulated dots (bit-identical chain to blas_emu_dot):
  // 7 threads per candidate, one kc=320 k-ascending FMA chain each; float4
  // loads; partials combined ascending with __fadd_rn. (Verbatim from r14.)
  for (int t = tid; t < m * NSEG; t += 256) {
    const int c = t / NSEG, s = t - (t / NSEG) * NSEG;
    const int kb = s * BLAS_KC;
    const int ke = (kb + BLAS_KC < DMODEL) ? kb + BLAS_KC : DMODEL;
    const float* wrow = Wg + (size_t)cidx[c] * DMODEL;
    const float4* xv = reinterpret_cast<const float4*>(xrow + kb);
    const float4* wv = reinterpret_cast<const float4*>(wrow + kb);
    float acc = 0.0f;
    const int nq = (ke - kb) >> 2;
    for (int q = 0; q < nq; ++q) {
      float4 a = xv[q], b = wv[q];
      acc = __builtin_fmaf(a.x, b.x, acc);
      acc = __builtin_fmaf(a.y, b.y, acc);
      acc = __builtin_fmaf(a.z, b.z, acc);
      acc = __builtin_fmaf(a.w, b.w, acc);
    }
    cpart[c][s] = acc;
  }
  __syncthreads();
  for (int c = tid; c < m; c += 256) {
    float ctot = cpart[c][0];
#pragma unroll
    for (int s = 1; s < NSEG; ++s) ctot = __fadd_rn(ctot, cpart[c][s]);
    cval[c] = ctot;
  }
  __syncthreads();

  // parallel rank selection: rank_c = #{c' lexicographically greater}; keep
  // rank < need. Identical set to the serial (val desc, idx asc) picks.
  for (int c = tid; c < m; c += 256) {
    const float vc = cval[c];
    const int ic = cidx[c];
    int rank = 0;
    for (int o = 0; o < m; ++o) {
      const float vo = cval[o];
      const int io = cidx[o];
      if (vo > vc || (vo == vc && io < ic)) ++rank;
    }
    if (rank < need) atomicOr(&bmap[ic >> 5], 1u << (ic & 31));
  }
  __syncthreads();
  Mask[(size_t)r * (H / 32) + tid] = bmap[tid];
}

// ---------------- mask + silu in-place on Hid (swizzled layout) -------------
__global__ __launch_bounds__(256)
void mask_silu(f16* __restrict__ P, const f16* __restrict__ G16,
               const unsigned* __restrict__ Msk, int n8) {
  const int stride = gridDim.x * blockDim.x;
  for (int i = blockIdx.x * blockDim.x + threadIdx.x; i < n8; i += stride) {
    const int row = i >> 10;
    const int gi = i & 1023;
    const int ls = (gi & 7) ^ (row & 7);
    const int c8l = ((gi >> 3) << 6) | (ls << 3);
    const unsigned mw = Msk[((size_t)row << 8) + (c8l >> 5)];
    const unsigned bits = (mw >> (c8l & 31)) & 0xFFu;
    half8v h = reinterpret_cast<half8v*>(P)[i];
    half8v g = reinterpret_cast<const half8v*>(G16)[i];
    half8v o;
#pragma unroll
    for (int j = 0; j < 8; ++j) {
      float gg = (float)g[j];
      float act = gg / (1.0f + __expf(-gg));
      o[j] = ((bits >> j) & 1u) ? (f16)((float)h[j] * act) : (f16)0.0f;
    }
    reinterpret_cast<half8v*>(P)[i] = o;
  }
}

// ---------------- down GEMM: out = p @ w_down^T (both f16, swizzled) --------
__global__ __launch_bounds__(256, 2)
void gemm_down(const f16* __restrict__ A, const f16* __restrict__ B16,
               float* __restrict__ C) {
  __shared__ f16 As[128 * 64];
  __shared__ f16 Bs[128 * 64];
  const int nwg = gridDim.x;
  const int bid = blockIdx.x;
  const int wg = (bid & 7) * (nwg >> 3) + (bid >> 3);
  const int NT = DMODEL >> 7;
  const int bm = wg / NT, bn = wg % NT;
  const int tid = threadIdx.x;
  const int w = tid >> 6, l = tid & 63;
  const int wr = w >> 1, wc = w & 1;
  const int lr = l >> 3, lc8 = (l & 7) << 3;

  f32x4 acc[4][4] = {};

  for (int kt = 0; kt < HIDDEN; kt += 64) {
    __syncthreads();
#pragma unroll
    for (int i = 0; i < 4; ++i) {
      const int row = i * 32 + w * 8;
      gload_lds16(A + (size_t)(bm * 128 + row + lr) * HIDDEN + kt + lc8, &As[row * 64]);
      gload_lds16(B16 + (size_t)(bn * 128 + row + lr) * HIDDEN + kt + lc8, &Bs[row * 64]);
    }
    __syncthreads();
#pragma unroll
    for (int ks = 0; ks < 2; ++ks) {
      half8v af[4], bf[4];
#pragma unroll
      for (int mf = 0; mf < 4; ++mf)
        af[mf] = frag_read(As, wr * 64 + mf * 16 + (l & 15), ks, l);
#pragma unroll
      for (int nf = 0; nf < 4; ++nf)
        bf[nf] = frag_read(Bs, wc * 64 + nf * 16 + (l & 15), ks, l);
#pragma unroll
      for (int mf = 0; mf < 4; ++mf)
#pragma unroll
        for (int nf = 0; nf < 4; ++nf)
          acc[mf][nf] = __builtin_amdgcn_mfma_f32_16x16x32_f16(af[mf], bf[nf], acc[mf][nf], 0, 0, 0);
    }
  }

  const int row0 = bm * 128 + wr * 64 + (l >> 4) * 4;
  const int col0 = bn * 128 + wc * 64 + (l & 15);
#pragma unroll
  for (int mf = 0; mf < 4; ++mf)
#pragma unroll
    for (int nf = 0; nf < 4; ++nf)
#pragma unroll
      for (int j = 0; j < 4; ++j)
        C[(size_t)(row0 + mf * 16 + j) * DMODEL + (col0 + nf * 16)] = acc[mf][nf][j];
}

// ---------------- launch ----------------
extern "C" void kernel_launch(void* const* d_in, const int* in_sizes, int n_in,
                              void* d_out, int out_size, void* d_ws, size_t ws_size,
                              hipStream_t stream) {
  const float* x = (const float*)d_in[0];
  const float* w_up = (const float*)d_in[1];
  const float* w_gate = (const float*)d_in[2];
  const float* w_down = (const float*)d_in[3];
  float* out = (float*)d_out;

  const size_t g_bytes = (size_t)NTOK * HIDDEN * 2;
  const size_t p_bytes = (size_t)NTOK * HIDDEN * 2;
  const size_t m_bytes = (size_t)NTOK * (HIDDEN / 32) * 4;
  const size_t x16_b = (size_t)NTOK * DMODEL * 2;
  const size_t wg16_b = (size_t)HIDDEN * DMODEL * 2;
  const size_t wu16_b = (size_t)HIDDEN * DMODEL * 2;
  const size_t wd16_b = (size_t)DMODEL * HIDDEN * 2;
  if (ws_size < g_bytes + p_bytes + m_bytes + x16_b + wg16_b + wu16_b + wd16_b) {
    hipMemsetAsync(d_out, 0, (size_t)out_size * 4, stream);
    return;
  }

  char* p = (char*)d_ws;
  f16* g16 = (f16*)p;       p += g_bytes;
  f16* pbuf = (f16*)p;      p += p_bytes;
  unsigned* msk = (unsigned*)p; p += m_bytes;
  f16* x16 = (f16*)p;       p += x16_b;
  f16* wg16 = (f16*)p;      p += wg16_b;
  f16* wu16 = (f16*)p;      p += wu16_b;
  f16* wd16 = (f16*)p;

  dim3 blk(256);

  cast_swz<<<2048, blk, 0, stream>>>(x, x16, DMODEL, NTOK * DMODEL / 8);
  cast_swz<<<2048, blk, 0, stream>>>(w_gate, wg16, DMODEL, HIDDEN * DMODEL / 8);
  cast_swz<<<2048, blk, 0, stream>>>(w_up, wu16, DMODEL, HIDDEN * DMODEL / 8);
  cast_swz<<<2048, blk, 0, stream>>>(w_down, wd16, HIDDEN, DMODEL * HIDDEN / 8);

  gemm_upgate<<<(NTOK / 128) * (HIDDEN / 128), blk, 0, stream>>>(
      x16, wg16, wu16, g16, pbuf);

  topk_mask<<<NTOK, blk, 0, stream>>>(g16, x, w_gate, msk, HIDDEN, TOPK_K);

  mask_silu<<<2048, blk, 0, stream>>>(pbuf, g16, msk, NTOK * HIDDEN / 8);

  gemm_down<<<(NTOK / 128) * (DMODEL / 128), blk, 0, stream>>>(pbuf, wd16, out);
}